// Round 9
// baseline (276.475 us; speedup 1.0000x reference)
//
#include <hip/hip_runtime.h>
#include <math.h>

// SGC: K=2 hops of D^-1/2 (A+I) D^-1/2, then x@W+b, then log_softmax.
// N=100000, D=64, C=40, E=1600000.
//
// R9: COLUMN-CHUNKED gather SpMM for per-XCD L2 locality.
//  - Cols split into 4 chunks (~3.2MB of bf16 rows each -> fits 4MiB L2).
//    CSR stores each row as 4 sorted, pad-4 mini-lists; vinfo[r] =
//    (start, plen0|plen1<<8|plen2<<16|plen3<<24).
//  - SpMM kernels are quasi-persistent: each wave owns WGROUPS=4 row-groups
//    (4 rows each, quarter-wave per row) and iterates CHUNK-MAJOR with all
//    16 accumulators in registers. Near-all-resident grid keeps waves
//    phase-aligned -> the chip streams one chunk at a time.
//  - Per-lane accumulate order = sorted cols + zero pads = deterministic,
//    bit-identical across replays (same guarantee as R7/R8).
//  - Buckets shrink to 256 rows (nb=391): 2x build_csr parallelism, 4 short
//    per-chunk insertion sorts per row.

#define D_FEAT 64
#define NCLS 40
#define BROWS 256       // rows per bucket
#define BROWS_LOG 8
#define BINCAP 4608     // per-bucket edge capacity (mean 4096, sd ~64 -> 8 sigma)
#define CSRCAP 7680     // per-bucket padded csr capacity (m + 3*1024 worst)
#define EPT 25          // edges per thread in bin_edges
#define NCHUNK 4
#define WGROUPS 4       // row-groups per wave in SpMM

__device__ __forceinline__ unsigned pack_bf16_2(float lo, float hi) {
    unsigned ulo = __float_as_uint(lo);
    unsigned uhi = __float_as_uint(hi);
    ulo = (ulo + 0x7fffu + ((ulo >> 16) & 1u)) >> 16;           // RNE
    uhi = (uhi + 0x7fffu + ((uhi >> 16) & 1u)) & 0xffff0000u;   // RNE
    return uhi | ulo;
}

__device__ __forceinline__ void acc2(unsigned u, float& a, float& b) {
    a += __uint_as_float(u << 16);
    b += __uint_as_float(u & 0xffff0000u);
}

__global__ void zero_cursors_kernel(int* __restrict__ cur, int nb) {
    int i = blockIdx.x * blockDim.x + threadIdx.x;
    if (i < nb) cur[i] = 0;
}

// Bin edges into per-bucket regions. Packed entry: (row&255)<<17 | col.
// (Requires n <= 131072 so col fits 17 bits; n = 100000 here.)
__global__ __launch_bounds__(256) void bin_edges_kernel(const int* __restrict__ rows,
                                                        const int* __restrict__ cols,
                                                        int* __restrict__ bucket_cursor,
                                                        unsigned* __restrict__ bins,
                                                        int e, int nb) {
    __shared__ int cnt[512];
    for (int i = threadIdx.x; i < nb; i += 256) cnt[i] = 0;
    __syncthreads();
    int base = blockIdx.x * (256 * EPT) + threadIdx.x;
    int rr[EPT], cc[EPT];
#pragma unroll
    for (int k = 0; k < EPT; k++) {
        int idx = base + k * 256;
        if (idx < e) { rr[k] = rows[idx]; cc[k] = cols[idx]; }
        else { rr[k] = -1; cc[k] = 0; }
    }
#pragma unroll
    for (int k = 0; k < EPT; k++)
        if (rr[k] >= 0) atomicAdd(&cnt[rr[k] >> BROWS_LOG], 1);
    __syncthreads();
    for (int i = threadIdx.x; i < nb; i += 256) {
        int c = cnt[i];
        cnt[i] = (c > 0) ? atomicAdd(&bucket_cursor[i], c) : 0;  // global base
    }
    __syncthreads();
#pragma unroll
    for (int k = 0; k < EPT; k++) {
        if (rr[k] >= 0) {
            int b = rr[k] >> BROWS_LOG;
            int pos = atomicAdd(&cnt[b], 1);  // absolute pos within bucket
            bins[(size_t)b * BINCAP + pos] =
                ((unsigned)(rr[k] & (BROWS - 1)) << 17) | (unsigned)cc[k];
        }
    }
}

// One 256-thread block per 256-row bucket. Virtual row = (row, chunk).
// Emits per-chunk sorted, pad-4 CSR (deterministic) + vinfo + dis.
__global__ __launch_bounds__(256) void build_csr_kernel(const unsigned* __restrict__ bins,
                                                        const int* __restrict__ bucket_cursor,
                                                        int* __restrict__ csr_col,
                                                        uint2* __restrict__ vinfo,
                                                        float* __restrict__ dis,
                                                        int n, int q1) {
    __shared__ int cnt[BROWS * NCHUNK];   // 4 KB
    __shared__ int cur[BROWS * NCHUNK];   // 4 KB
    __shared__ int sm[BROWS];             // 1 KB
    __shared__ int lcsr[CSRCAP];          // 30 KB
    int b = blockIdx.x;
    int tid = threadIdx.x;
    int m = bucket_cursor[b];
    const int q2 = 2 * q1, q3 = 3 * q1;
    for (int i = tid; i < BROWS * NCHUNK; i += 256) cnt[i] = 0;
    __syncthreads();
    const unsigned* bp = bins + (size_t)b * BINCAP;
    for (int i = tid; i < m; i += 256) {
        unsigned u = bp[i];
        int col = (int)(u & 0x1FFFFu);
        int ch = (col >= q2) ? ((col >= q3) ? 3 : 2) : ((col >= q1) ? 1 : 0);
        atomicAdd(&cnt[(u >> 17) * NCHUNK + ch], 1);
    }
    __syncthreads();
    int c0 = cnt[tid * 4 + 0], c1 = cnt[tid * 4 + 1];
    int c2 = cnt[tid * 4 + 2], c3 = cnt[tid * 4 + 3];
    int p0 = (c0 + 3) & ~3, p1 = (c1 + 3) & ~3, p2 = (c2 + 3) & ~3, p3 = (c3 + 3) & ~3;
    int T = p0 + p1 + p2 + p3;
    int r = b * BROWS + tid;
    if (r < n) dis[r] = rsqrtf(1.0f + (float)(c0 + c1 + c2 + c3));
    sm[tid] = T;
    __syncthreads();
    for (int off = 1; off < 256; off <<= 1) {
        int t = (tid >= off) ? sm[tid - off] : 0;
        __syncthreads();
        sm[tid] += t;
        __syncthreads();
    }
    int off0 = sm[tid] - T;  // exclusive scan (bucket-relative)
    int s0 = off0, s1 = s0 + p0, s2 = s1 + p1, s3 = s2 + p2;
    cur[tid * 4 + 0] = s0; cur[tid * 4 + 1] = s1;
    cur[tid * 4 + 2] = s2; cur[tid * 4 + 3] = s3;
    if (r < n)
        vinfo[r] = make_uint2((unsigned)(b * CSRCAP + off0),
                              (unsigned)(p0 | (p1 << 8) | (p2 << 16) | (p3 << 24)));
    __syncthreads();
    for (int i = tid; i < m; i += 256) {
        unsigned u = bp[i];
        int col = (int)(u & 0x1FFFFu);
        int ch = (col >= q2) ? ((col >= q3) ? 3 : 2) : ((col >= q1) ? 1 : 0);
        int pos = atomicAdd(&cur[(u >> 17) * NCHUNK + ch], 1);
        lcsr[pos] = col;
    }
    __syncthreads();
    // Per-(row,chunk) insertion sort (determinism) + dummy pad.
    int st[4] = {s0, s1, s2, s3};
    int cc[4] = {c0, c1, c2, c3};
    int pp[4] = {p0, p1, p2, p3};
#pragma unroll
    for (int k = 0; k < 4; k++) {
        int base = st[k], c = cc[k], p = pp[k];
        for (int i2 = base + 1; i2 < base + c; i2++) {
            int key = lcsr[i2];
            int j = i2 - 1;
            while (j >= base && lcsr[j] > key) { lcsr[j + 1] = lcsr[j]; j--; }
            lcsr[j + 1] = key;
        }
        for (int j = base + c; j < base + p; j++) lcsr[j] = n;
    }
    __syncthreads();
    int tot = sm[255];  // total padded slots (multiple of 4)
    int4* cp4 = (int4*)(csr_col + (size_t)b * CSRCAP);
    const int4* l4 = (const int4*)lcsr;
    for (int i = tid; i < (tot >> 2); i += 256) cp4[i] = l4[i];
}

// xs0[i] = bf16(dis[i] * x[i,:]) packed 2/dword; dummy rows (n) of BOTH xs
// arrays zeroed (pad slots gather row n).
__global__ void scale_x_kernel(const float* __restrict__ x, const float* __restrict__ dis,
                               unsigned* __restrict__ xs0, unsigned* __restrict__ xs1, int n) {
    int i = blockIdx.x * blockDim.x + threadIdx.x;  // over (n+1)*32 dwords
    int total = (n + 1) * (D_FEAT / 2);
    if (i >= total) return;
    int node = i >> 5;
    if (node < n) {
        float s = dis[node];
        float2 v = ((const float2*)x)[i];
        xs0[i] = pack_bf16_2(s * v.x, s * v.y);
    } else {
        xs0[i] = 0u;
        xs1[i] = 0u;  // dummy row of hop-1 output
    }
}

// Gather up to 8 slots (2 groups of 4) of one quarter's chunk list.
__device__ __forceinline__ void gather8(const uint4* __restrict__ cp,
                                        const uint2* __restrict__ xs, int ql,
                                        int base, int plen,
                                        float& h0, float& h1, float& h2, float& h3) {
    uint4 cv = cp[base >> 2];
    uint2 u0 = xs[cv.x * 16 + ql];
    uint2 u1 = xs[cv.y * 16 + ql];
    uint2 u2 = xs[cv.z * 16 + ql];
    uint2 u3 = xs[cv.w * 16 + ql];
    uint2 u4 = make_uint2(0u, 0u), u5 = u4, u6 = u4, u7 = u4;
    if (base + 4 < plen) {
        uint4 cv2 = cp[(base >> 2) + 1];
        u4 = xs[cv2.x * 16 + ql];
        u5 = xs[cv2.y * 16 + ql];
        u6 = xs[cv2.z * 16 + ql];
        u7 = xs[cv2.w * 16 + ql];
    }
    acc2(u0.x, h0, h1); acc2(u0.y, h2, h3);
    acc2(u1.x, h0, h1); acc2(u1.y, h2, h3);
    acc2(u2.x, h0, h1); acc2(u2.y, h2, h3);
    acc2(u3.x, h0, h1); acc2(u3.y, h2, h3);
    acc2(u4.x, h0, h1); acc2(u4.y, h2, h3);
    acc2(u5.x, h0, h1); acc2(u5.y, h2, h3);
    acc2(u6.x, h0, h1); acc2(u6.y, h2, h3);
    acc2(u7.x, h0, h1); acc2(u7.y, h2, h3);
}

// Hop 1: xs1[r,:] = bf16( dis[r]^2 * ( xs0[r,:] + sum_c xs0[c,:] ) ).
// Quasi-persistent: wave w owns row-groups g*gstride+w, g<WGROUPS; chunk-major.
__global__ __launch_bounds__(256) void spmm_hop1_kernel(const uint2* __restrict__ xs_in,
                                                        uint2* __restrict__ xs_out,
                                                        const uint2* __restrict__ vinfo,
                                                        const int* __restrict__ csr_col,
                                                        const float* __restrict__ dis,
                                                        int n, int gstride) {
    int w = blockIdx.x * 4 + (threadIdx.x >> 6);
    int lane = threadIdx.x & 63;
    int q = lane >> 4, ql = lane & 15;

    int rr[WGROUPS]; int cs[WGROUPS]; unsigned pl[WGROUPS];
    float h[WGROUPS][4];
#pragma unroll
    for (int g = 0; g < WGROUPS; g++) {
        int rg = g * gstride + w;
        int r = rg * 4 + q;
        rr[g] = r;
        if (r < n) { uint2 iv = vinfo[r]; cs[g] = (int)iv.x; pl[g] = iv.y; }
        else { cs[g] = 0; pl[g] = 0u; }
        h[g][0] = h[g][1] = h[g][2] = h[g][3] = 0.f;
    }
#pragma unroll
    for (int k = 0; k < NCHUNK; k++) {
#pragma unroll
        for (int g = 0; g < WGROUPS; g++) {
            int plen = (int)((pl[g] >> (8 * k)) & 0xFFu);
            const uint4* cp = (const uint4*)(csr_col + cs[g]);
            for (int base = 0; base < plen; base += 8)
                gather8(cp, xs_in, ql, base, plen, h[g][0], h[g][1], h[g][2], h[g][3]);
            cs[g] += plen;
        }
    }
#pragma unroll
    for (int g = 0; g < WGROUPS; g++) {
        int r = rr[g];
        if (r < n) {
            uint2 us = xs_in[r * 16 + ql];  // self term
            acc2(us.x, h[g][0], h[g][1]); acc2(us.y, h[g][2], h[g][3]);
            float dr = dis[r];
            float dr2 = dr * dr;
            xs_out[r * 16 + ql] = make_uint2(pack_bf16_2(dr2 * h[g][0], dr2 * h[g][1]),
                                             pack_bf16_2(dr2 * h[g][2], dr2 * h[g][3]));
        }
    }
}

// Hop 2 fused with logits + log_softmax, same quasi-persistent chunk-major walk.
__global__ __launch_bounds__(256) void spmm_logits_kernel(const uint2* __restrict__ xs_in,
                                                          const uint2* __restrict__ vinfo,
                                                          const int* __restrict__ csr_col,
                                                          const float* __restrict__ dis,
                                                          const float* __restrict__ W,
                                                          const float* __restrict__ b,
                                                          float* __restrict__ out,
                                                          int n, int gstride) {
    __shared__ float Wl[D_FEAT * NCLS];
    __shared__ float bl[NCLS];
    for (int i = threadIdx.x; i < D_FEAT * NCLS; i += blockDim.x) Wl[i] = W[i];
    for (int i = threadIdx.x; i < NCLS; i += blockDim.x) bl[i] = b[i];
    __syncthreads();

    int w = blockIdx.x * 4 + (threadIdx.x >> 6);
    int lane = threadIdx.x & 63;
    int q = lane >> 4, ql = lane & 15;

    int rr[WGROUPS]; int cs[WGROUPS]; unsigned pl[WGROUPS];
    float h[WGROUPS][4];
#pragma unroll
    for (int g = 0; g < WGROUPS; g++) {
        int rg = g * gstride + w;
        int r = rg * 4 + q;
        rr[g] = r;
        if (r < n) { uint2 iv = vinfo[r]; cs[g] = (int)iv.x; pl[g] = iv.y; }
        else { cs[g] = 0; pl[g] = 0u; }
        h[g][0] = h[g][1] = h[g][2] = h[g][3] = 0.f;
    }
#pragma unroll
    for (int k = 0; k < NCHUNK; k++) {
#pragma unroll
        for (int g = 0; g < WGROUPS; g++) {
            int plen = (int)((pl[g] >> (8 * k)) & 0xFFu);
            const uint4* cp = (const uint4*)(csr_col + cs[g]);
            for (int base = 0; base < plen; base += 8)
                gather8(cp, xs_in, ql, base, plen, h[g][0], h[g][1], h[g][2], h[g][3]);
            cs[g] += plen;
        }
    }

#pragma unroll
    for (int g = 0; g < WGROUPS; g++) {
        int r = rr[g];
        bool valid = r < n;
        float h0 = h[g][0], h1 = h[g][1], h2 = h[g][2], h3 = h[g][3];
        uint2 us = valid ? xs_in[r * 16 + ql] : make_uint2(0u, 0u);  // self term
        acc2(us.x, h0, h1); acc2(us.y, h2, h3);
        float dr = valid ? dis[r] : 0.f;
        h0 *= dr; h1 *= dr; h2 *= dr; h3 *= dr;

        // GEMV: lane ql covers classes ql, ql+16, (ql<8) ql+32; features
        // broadcast via per-lane-source shfl within the quarter.
        int c0 = ql, c1 = ql + 16;
        int c2 = (ql < 8) ? (ql + 32) : ql;  // dup addr -> broadcast, no conflict
        float y0 = bl[c0], y1 = bl[c1], y2 = bl[c2];
        int qbase = q << 4;
#pragma unroll
        for (int d = 0; d < D_FEAT; d++) {
            int src = qbase + (d >> 2);
            float xv;
            switch (d & 3) {
                case 0: xv = __shfl(h0, src, 64); break;
                case 1: xv = __shfl(h1, src, 64); break;
                case 2: xv = __shfl(h2, src, 64); break;
                default: xv = __shfl(h3, src, 64); break;
            }
            y0 += xv * Wl[d * NCLS + c0];
            y1 += xv * Wl[d * NCLS + c1];
            y2 += xv * Wl[d * NCLS + c2];
        }

        bool has3 = (ql < 8);
        float m = fmaxf(y0, y1);
        if (has3) m = fmaxf(m, y2);
#pragma unroll
        for (int o = 8; o > 0; o >>= 1) m = fmaxf(m, __shfl_xor(m, o, 64));
        float sm = __expf(y0 - m) + __expf(y1 - m) + (has3 ? __expf(y2 - m) : 0.f);
#pragma unroll
        for (int o = 8; o > 0; o >>= 1) sm += __shfl_xor(sm, o, 64);
        float lse = m + __logf(sm);

        if (valid) {
            float* op = out + (long long)r * NCLS;
            op[ql] = y0 - lse;
            op[ql + 16] = y1 - lse;
            if (has3) op[ql + 32] = y2 - lse;
        }
    }
}

extern "C" void kernel_launch(void* const* d_in, const int* in_sizes, int n_in,
                              void* d_out, int out_size, void* d_ws, size_t ws_size,
                              hipStream_t stream) {
    const float* x  = (const float*)d_in[0];
    const int*   ei = (const int*)d_in[1];   // [2, E] flat: rows then cols (int32)
    const float* W  = (const float*)d_in[2]; // [64, 40]
    const float* b  = (const float*)d_in[3]; // [40]
    float* out = (float*)d_out;

    const int n = in_sizes[0] / D_FEAT;      // 100000
    const int e = in_sizes[1] / 2;           // 1600000
    const int nb = (n + BROWS - 1) / BROWS;  // 391
    const int q1 = (n + NCHUNK - 1) / NCHUNK;

    const int* rows = ei;
    const int* cols = ei + e;

    // ws layout (int units, all segments 256-int aligned):
    //   bucket_cursor[512] | dis[n] | vinfo[n] (uint2) |
    //   bins[nb*BINCAP] | csr_col[nb*CSRCAP] | xs0 | xs1      (~47 MB)
    size_t na = ((size_t)n + 256) & ~(size_t)255;
    int*      bucket_cursor = (int*)d_ws;
    float*    dis           = (float*)(bucket_cursor + 512);
    uint2*    vinfo         = (uint2*)(dis + na);
    unsigned* bins          = (unsigned*)(vinfo + na);
    int*      csr_col       = (int*)(bins + (size_t)nb * BINCAP);
    unsigned* xs0           = (unsigned*)(csr_col + (size_t)nb * CSRCAP);
    unsigned* xs1           = xs0 + (size_t)(n + 1) * (D_FEAT / 2);

    const int BS = 256;

    zero_cursors_kernel<<<2, 256, 0, stream>>>(bucket_cursor, nb);
    {
        int blocks = (e + BS * EPT - 1) / (BS * EPT);  // 250
        bin_edges_kernel<<<blocks, BS, 0, stream>>>(rows, cols, bucket_cursor, bins, e, nb);
    }
    build_csr_kernel<<<nb, BS, 0, stream>>>(bins, bucket_cursor, csr_col, vinfo, dis, n, q1);
    {
        int tot = (n + 1) * (D_FEAT / 2);
        scale_x_kernel<<<(tot + BS - 1) / BS, BS, 0, stream>>>(x, dis, xs0, xs1, n);
    }

    int nwaves = (n + 3) / 4;                           // 25000 row-groups
    int gstride = (nwaves + WGROUPS - 1) / WGROUPS;     // 6250 waves launched
    int blocks = (gstride * 64 + BS - 1) / BS;          // 1563 blocks
    spmm_hop1_kernel<<<blocks, BS, 0, stream>>>((const uint2*)xs0, (uint2*)xs1,
                                                vinfo, csr_col, dis, n, gstride);
    spmm_logits_kernel<<<blocks, BS, 0, stream>>>((const uint2*)xs1, vinfo, csr_col,
                                                  dis, W, b, out, n, gstride);
}

// Round 10
// 263.110 us; speedup vs baseline: 1.0508x; 1.0508x over previous
//
#include <hip/hip_runtime.h>
#include <math.h>

// SGC: K=2 hops of D^-1/2 (A+I) D^-1/2, then x@W+b, then log_softmax.
// N=100000, D=64, C=40, E=1600000.
//
// R10: R8's flat SpMM (best measured: 66us/hop) + atomic-free binning.
//  - SpMM: quarter-wave per row (16 lanes x uint2 = one 128B bf16 row),
//    4 predicated groups of 4 slots -> 16 row-gathers in flight per wave,
//    25000 waves (fine-grain balance). [R9's chunked/persistent variant
//    regressed: occupancy 68->31%, concurrency loss > latency gain.]
//  - Binning is 3-phase, NO global atomics (R5/R6 lesson: cross-XCD atomic
//    lines are poison): count -> per-bucket scan of per-block counts ->
//    scatter with LDS cursors seeded from scanned bases. Deterministic.
//  - build_csr: per-bucket LDS build, per-row insertion sort (deterministic
//    sorted order -> bit-identical output across replays), int4 copy-out,
//    PLUS fused per-bucket xs0 scaling (removes scale_x kernel).

#define D_FEAT 64
#define NCLS 40
#define BROWS 512       // rows per bucket
#define BROWS_LOG 9
#define BINCAP 10240    // per-bucket edge capacity (mean 8192, sd ~90)
#define CSRCAP 12288    // per-bucket csr capacity (max padded = 10240+3*512)
#define EPT 25          // edges per thread in binning kernels
#define NBLK 256        // padded per-bucket block-count stride (>= 250)

__device__ __forceinline__ unsigned pack_bf16_2(float lo, float hi) {
    unsigned ulo = __float_as_uint(lo);
    unsigned uhi = __float_as_uint(hi);
    ulo = (ulo + 0x7fffu + ((ulo >> 16) & 1u)) >> 16;           // RNE
    uhi = (uhi + 0x7fffu + ((uhi >> 16) & 1u)) & 0xffff0000u;   // RNE
    return uhi | ulo;
}

__device__ __forceinline__ void acc2(unsigned u, float& a, float& b) {
    a += __uint_as_float(u << 16);
    b += __uint_as_float(u & 0xffff0000u);
}

// Phase A: per-(block,bucket) edge counts. blockcounts[bkt*NBLK + blk].
__global__ __launch_bounds__(256) void count_edges_kernel(const int* __restrict__ rows,
                                                          int* __restrict__ blockcounts,
                                                          int e, int nb) {
    __shared__ int cnt[512];
    for (int i = threadIdx.x; i < nb; i += 256) cnt[i] = 0;
    __syncthreads();
    int base = blockIdx.x * (256 * EPT) + threadIdx.x;
#pragma unroll
    for (int k = 0; k < EPT; k++) {
        int idx = base + k * 256;
        if (idx < e) atomicAdd(&cnt[rows[idx] >> BROWS_LOG], 1);
    }
    __syncthreads();
    for (int i = threadIdx.x; i < nb; i += 256)
        blockcounts[i * NBLK + blockIdx.x] = cnt[i];
}

// Phase B: per-bucket exclusive scan of the per-block counts; emits totals.
__global__ __launch_bounds__(256) void scan_bases_kernel(int* __restrict__ blockcounts,
                                                         int* __restrict__ bucket_total,
                                                         int nblocks) {
    __shared__ int sm[256];
    int b = blockIdx.x;
    int t = threadIdx.x;
    int v = (t < nblocks) ? blockcounts[b * NBLK + t] : 0;
    sm[t] = v;
    __syncthreads();
    for (int off = 1; off < 256; off <<= 1) {
        int x = (t >= off) ? sm[t - off] : 0;
        __syncthreads();
        sm[t] += x;
        __syncthreads();
    }
    if (t < nblocks) blockcounts[b * NBLK + t] = sm[t] - v;  // exclusive base
    if (t == 255) bucket_total[b] = sm[255];
}

// Phase C: scatter edges into per-bucket bins using scanned bases (no global
// atomics). Packed entry: (row&511)<<17 | col. (n <= 131072 so col fits 17b.)
__global__ __launch_bounds__(256) void scatter_edges_kernel(const int* __restrict__ rows,
                                                            const int* __restrict__ cols,
                                                            const int* __restrict__ blockcounts,
                                                            unsigned* __restrict__ bins,
                                                            int e, int nb) {
    __shared__ int cur[512];
    for (int i = threadIdx.x; i < nb; i += 256)
        cur[i] = blockcounts[i * NBLK + blockIdx.x];
    __syncthreads();
    int base = blockIdx.x * (256 * EPT) + threadIdx.x;
#pragma unroll
    for (int k = 0; k < EPT; k++) {
        int idx = base + k * 256;
        if (idx < e) {
            int r = rows[idx];
            int b = r >> BROWS_LOG;
            int pos = atomicAdd(&cur[b], 1);  // LDS atomic only
            bins[(size_t)b * BINCAP + pos] =
                ((unsigned)(r & (BROWS - 1)) << 17) | (unsigned)cols[idx];
        }
    }
}

// One 512-thread block per bucket: LDS count -> dis; scan (pad-4); LDS
// scatter; per-row insertion sort (determinism); int4 copy-out; FUSED xs0
// scaling of this bucket's rows. Block 0 also zeroes the dummy rows.
__global__ __launch_bounds__(512) void build_csr_kernel(const unsigned* __restrict__ bins,
                                                        const int* __restrict__ bucket_total,
                                                        const float* __restrict__ x,
                                                        int* __restrict__ csr_col,
                                                        uint2* __restrict__ row_info,
                                                        float* __restrict__ dis,
                                                        unsigned* __restrict__ xs0,
                                                        unsigned* __restrict__ xs1, int n) {
    __shared__ int cnt[512];
    __shared__ int sm[512];
    __shared__ int cur[512];
    __shared__ float disl[512];
    __shared__ int lcsr[CSRCAP];  // 48 KB
    int b = blockIdx.x;
    int tid = threadIdx.x;
    int m = bucket_total[b];
    cnt[tid] = 0;
    __syncthreads();
    const unsigned* bp = bins + (size_t)b * BINCAP;
    for (int i = tid; i < m; i += 512) atomicAdd(&cnt[bp[i] >> 17], 1);
    __syncthreads();
    int c = cnt[tid];
    int padded = (c + 3) & ~3;
    int r = b * BROWS + tid;
    float dv = rsqrtf(1.0f + (float)c);
    disl[tid] = dv;
    if (r < n) dis[r] = dv;
    sm[tid] = padded;
    __syncthreads();
    for (int off = 1; off < 512; off <<= 1) {
        int t = (tid >= off) ? sm[tid - off] : 0;
        __syncthreads();
        sm[tid] += t;
        __syncthreads();
    }
    int off0 = sm[tid] - padded;  // exclusive scan
    cur[tid] = off0;
    if (r < n) row_info[r] = make_uint2((unsigned)(b * CSRCAP + off0), (unsigned)padded);
    __syncthreads();
    for (int i = tid; i < m; i += 512) {
        unsigned u = bp[i];
        int pos = atomicAdd(&cur[u >> 17], 1);
        lcsr[pos] = (int)(u & 0x1FFFFu);
    }
    __syncthreads();
    // Per-row insertion sort (deterministic multiset order) + dummy pad.
    for (int i2 = off0 + 1; i2 < off0 + c; i2++) {
        int key = lcsr[i2];
        int j = i2 - 1;
        while (j >= off0 && lcsr[j] > key) { lcsr[j + 1] = lcsr[j]; j--; }
        lcsr[j + 1] = key;
    }
    for (int j = off0 + c; j < off0 + padded; j++) lcsr[j] = n;
    __syncthreads();
    int tot = sm[511];  // total padded slots (multiple of 4)
    int4* cp4 = (int4*)(csr_col + (size_t)b * CSRCAP);
    const int4* l4 = (const int4*)lcsr;
    for (int i = tid; i < (tot >> 2); i += 512) cp4[i] = l4[i];

    // Fused scale: xs0[g,:] = bf16(dis[g] * x[g,:]) for this bucket's rows.
    // Linear over the bucket's 512*32 dwords, coalesced.
    int dwbase = b * (BROWS * 32);
    for (int i = tid; i < BROWS * 32; i += 512) {
        int g = b * BROWS + (i >> 5);
        if (g < n) {
            float s = disl[i >> 5];
            float2 v = ((const float2*)x)[dwbase + i];
            xs0[dwbase + i] = pack_bf16_2(s * v.x, s * v.y);
        }
    }
    if (b == 0 && tid < 32) {  // dummy row n of both xs arrays
        xs0[(size_t)n * 32 + tid] = 0u;
        xs1[(size_t)n * 32 + tid] = 0u;
    }
}

// Gather 16 slots (4 predicated groups of 4) for one quarter's row chunk.
#define GATHER16(cp, xs_in, ql, base, len)                                  \
    uint2 u0 = make_uint2(0u, 0u), u1 = u0, u2 = u0, u3 = u0;               \
    uint2 u4 = u0, u5 = u0, u6 = u0, u7 = u0;                               \
    uint2 u8 = u0, u9 = u0, u10 = u0, u11 = u0;                             \
    uint2 u12 = u0, u13 = u0, u14 = u0, u15 = u0;                           \
    if (base < len) {                                                       \
        uint4 cv = cp[(base >> 2) + 0];                                     \
        u0 = xs_in[cv.x * 16 + ql]; u1 = xs_in[cv.y * 16 + ql];             \
        u2 = xs_in[cv.z * 16 + ql]; u3 = xs_in[cv.w * 16 + ql];             \
    }                                                                       \
    if (base + 4 < len) {                                                   \
        uint4 cv = cp[(base >> 2) + 1];                                     \
        u4 = xs_in[cv.x * 16 + ql]; u5 = xs_in[cv.y * 16 + ql];             \
        u6 = xs_in[cv.z * 16 + ql]; u7 = xs_in[cv.w * 16 + ql];             \
    }                                                                       \
    if (base + 8 < len) {                                                   \
        uint4 cv = cp[(base >> 2) + 2];                                     \
        u8 = xs_in[cv.x * 16 + ql]; u9 = xs_in[cv.y * 16 + ql];             \
        u10 = xs_in[cv.z * 16 + ql]; u11 = xs_in[cv.w * 16 + ql];           \
    }                                                                       \
    if (base + 12 < len) {                                                  \
        uint4 cv = cp[(base >> 2) + 3];                                     \
        u12 = xs_in[cv.x * 16 + ql]; u13 = xs_in[cv.y * 16 + ql];           \
        u14 = xs_in[cv.z * 16 + ql]; u15 = xs_in[cv.w * 16 + ql];           \
    }                                                                       \
    acc2(u0.x, h0, h1); acc2(u0.y, h2, h3);                                 \
    acc2(u1.x, h0, h1); acc2(u1.y, h2, h3);                                 \
    acc2(u2.x, h0, h1); acc2(u2.y, h2, h3);                                 \
    acc2(u3.x, h0, h1); acc2(u3.y, h2, h3);                                 \
    acc2(u4.x, h0, h1); acc2(u4.y, h2, h3);                                 \
    acc2(u5.x, h0, h1); acc2(u5.y, h2, h3);                                 \
    acc2(u6.x, h0, h1); acc2(u6.y, h2, h3);                                 \
    acc2(u7.x, h0, h1); acc2(u7.y, h2, h3);                                 \
    acc2(u8.x, h0, h1); acc2(u8.y, h2, h3);                                 \
    acc2(u9.x, h0, h1); acc2(u9.y, h2, h3);                                 \
    acc2(u10.x, h0, h1); acc2(u10.y, h2, h3);                               \
    acc2(u11.x, h0, h1); acc2(u11.y, h2, h3);                               \
    acc2(u12.x, h0, h1); acc2(u12.y, h2, h3);                               \
    acc2(u13.x, h0, h1); acc2(u13.y, h2, h3);                               \
    acc2(u14.x, h0, h1); acc2(u14.y, h2, h3);                               \
    acc2(u15.x, h0, h1); acc2(u15.y, h2, h3);

// Hop 1: xs1[r,:] = bf16( dis[r]^2 * ( xs0[r,:] + sum_c xs0[c,:] ) ).
// Quarter q owns row 4*wave+q; lane (q,ql) holds features 4ql..4ql+3.
__global__ __launch_bounds__(256) void spmm_hop1_kernel(const uint2* __restrict__ xs_in,
                                                        uint2* __restrict__ xs_out,
                                                        const uint2* __restrict__ row_info,
                                                        const int* __restrict__ csr_col,
                                                        const float* __restrict__ dis, int n) {
    int wave = (blockIdx.x * blockDim.x + threadIdx.x) >> 6;
    int lane = threadIdx.x & 63;
    int q = lane >> 4, ql = lane & 15;
    int r = wave * 4 + q;
    bool valid = r < n;
    int s = 0, len = 0;
    if (valid) { uint2 info = row_info[r]; s = (int)info.x; len = (int)info.y; }
    int maxlen = len;
    maxlen = max(maxlen, __shfl_xor(maxlen, 16, 64));
    maxlen = max(maxlen, __shfl_xor(maxlen, 32, 64));

    float h0 = 0.f, h1 = 0.f, h2 = 0.f, h3 = 0.f;
    const uint4* cp = (const uint4*)(csr_col + s);  // s is a multiple of 4
    for (int base = 0; base < maxlen; base += 16) {
        GATHER16(cp, xs_in, ql, base, len)
    }
    if (valid) {
        uint2 us = xs_in[r * 16 + ql];  // self term
        acc2(us.x, h0, h1); acc2(us.y, h2, h3);
        float dr = dis[r];
        float dr2 = dr * dr;
        xs_out[r * 16 + ql] = make_uint2(pack_bf16_2(dr2 * h0, dr2 * h1),
                                         pack_bf16_2(dr2 * h2, dr2 * h3));
    }
}

// Hop 2 fused with logits + log_softmax. h2[r,:] = dis[r]*(xs1[r,:]+sum_c xs1[c,:]).
// GEMV: lane ql covers classes ql, ql+16, (ql<8) ql+32; features broadcast via
// per-lane-source __shfl within the quarter.
__global__ __launch_bounds__(256) void spmm_logits_kernel(const uint2* __restrict__ xs_in,
                                                          const uint2* __restrict__ row_info,
                                                          const int* __restrict__ csr_col,
                                                          const float* __restrict__ dis,
                                                          const float* __restrict__ W,
                                                          const float* __restrict__ b,
                                                          float* __restrict__ out, int n) {
    __shared__ float Wl[D_FEAT * NCLS];
    __shared__ float bl[NCLS];
    for (int i = threadIdx.x; i < D_FEAT * NCLS; i += blockDim.x) Wl[i] = W[i];
    for (int i = threadIdx.x; i < NCLS; i += blockDim.x) bl[i] = b[i];
    __syncthreads();

    int wave = (blockIdx.x * blockDim.x + threadIdx.x) >> 6;
    int lane = threadIdx.x & 63;
    int q = lane >> 4, ql = lane & 15;
    int r = wave * 4 + q;
    bool valid = r < n;
    int s = 0, len = 0;
    if (valid) { uint2 info = row_info[r]; s = (int)info.x; len = (int)info.y; }
    int maxlen = len;
    maxlen = max(maxlen, __shfl_xor(maxlen, 16, 64));
    maxlen = max(maxlen, __shfl_xor(maxlen, 32, 64));

    float h0 = 0.f, h1 = 0.f, h2 = 0.f, h3 = 0.f;
    const uint4* cp = (const uint4*)(csr_col + s);
    for (int base = 0; base < maxlen; base += 16) {
        GATHER16(cp, xs_in, ql, base, len)
    }

    float y0, y1, y2;
    {
        uint2 us = valid ? xs_in[r * 16 + ql] : make_uint2(0u, 0u);  // self term
        acc2(us.x, h0, h1); acc2(us.y, h2, h3);
        float dr = valid ? dis[r] : 0.f;
        h0 *= dr; h1 *= dr; h2 *= dr; h3 *= dr;

        int c0 = ql, c1 = ql + 16;
        int c2 = (ql < 8) ? (ql + 32) : ql;  // dup addr -> broadcast, no conflict
        y0 = bl[c0]; y1 = bl[c1]; y2 = bl[c2];
        int qbase = q << 4;
#pragma unroll
        for (int d = 0; d < D_FEAT; d++) {
            int src = qbase + (d >> 2);
            float xv;
            switch (d & 3) {
                case 0: xv = __shfl(h0, src, 64); break;
                case 1: xv = __shfl(h1, src, 64); break;
                case 2: xv = __shfl(h2, src, 64); break;
                default: xv = __shfl(h3, src, 64); break;
            }
            y0 += xv * Wl[d * NCLS + c0];
            y1 += xv * Wl[d * NCLS + c1];
            y2 += xv * Wl[d * NCLS + c2];
        }
    }

    bool has3 = (ql < 8);
    float m = fmaxf(y0, y1);
    if (has3) m = fmaxf(m, y2);
#pragma unroll
    for (int o = 8; o > 0; o >>= 1) m = fmaxf(m, __shfl_xor(m, o, 64));
    float sm = __expf(y0 - m) + __expf(y1 - m) + (has3 ? __expf(y2 - m) : 0.f);
#pragma unroll
    for (int o = 8; o > 0; o >>= 1) sm += __shfl_xor(sm, o, 64);
    float lse = m + __logf(sm);

    if (valid) {
        float* op = out + (long long)r * NCLS;
        op[ql] = y0 - lse;
        op[ql + 16] = y1 - lse;
        if (has3) op[ql + 32] = y2 - lse;
    }
}

extern "C" void kernel_launch(void* const* d_in, const int* in_sizes, int n_in,
                              void* d_out, int out_size, void* d_ws, size_t ws_size,
                              hipStream_t stream) {
    const float* x  = (const float*)d_in[0];
    const int*   ei = (const int*)d_in[1];   // [2, E] flat: rows then cols (int32)
    const float* W  = (const float*)d_in[2]; // [64, 40]
    const float* b  = (const float*)d_in[3]; // [40]
    float* out = (float*)d_out;

    const int n = in_sizes[0] / D_FEAT;      // 100000
    const int e = in_sizes[1] / 2;           // 1600000
    const int nb = (n + BROWS - 1) / BROWS;  // 196
    const int eblocks = (e + 256 * EPT - 1) / (256 * EPT);  // 250

    const int* rows = ei;
    const int* cols = ei + e;

    // ws layout (int units, segments 256-int aligned):
    //   bucket_total[256] | blockcounts[nb*NBLK] | dis[n] | row_info[n] |
    //   bins[nb*BINCAP] | csr_col[nb*CSRCAP] | xs0 | xs1     (~45 MB)
    size_t na = ((size_t)n + 256) & ~(size_t)255;
    int*      bucket_total = (int*)d_ws;
    int*      blockcounts  = bucket_total + 256;
    float*    dis          = (float*)(blockcounts + (size_t)nb * NBLK + 256);
    uint2*    row_info     = (uint2*)(dis + na);
    unsigned* bins         = (unsigned*)(row_info + na);
    int*      csr_col      = (int*)(bins + (size_t)nb * BINCAP);
    unsigned* xs0          = (unsigned*)(csr_col + (size_t)nb * CSRCAP);
    unsigned* xs1          = xs0 + (size_t)(n + 1) * (D_FEAT / 2);

    const int BS = 256;

    count_edges_kernel<<<eblocks, BS, 0, stream>>>(rows, blockcounts, e, nb);
    scan_bases_kernel<<<nb, BS, 0, stream>>>(blockcounts, bucket_total, eblocks);
    scatter_edges_kernel<<<eblocks, BS, 0, stream>>>(rows, cols, blockcounts, bins, e, nb);
    build_csr_kernel<<<nb, 512, 0, stream>>>(bins, bucket_total, x, csr_col, row_info,
                                             dis, xs0, xs1, n);

    int nwaves = (n + 3) / 4;                 // 25000 waves, 4 rows each
    int blocks = (nwaves * 64 + BS - 1) / BS; // 6250
    spmm_hop1_kernel<<<blocks, BS, 0, stream>>>((const uint2*)xs0, (uint2*)xs1,
                                                row_info, csr_col, dis, n);
    spmm_logits_kernel<<<blocks, BS, 0, stream>>>((const uint2*)xs1, row_info, csr_col,
                                                  dis, W, b, out, n);
}

// Round 11
// 255.312 us; speedup vs baseline: 1.0829x; 1.0305x over previous
//
#include <hip/hip_runtime.h>
#include <math.h>

// SGC: K=2 hops of D^-1/2 (A+I) D^-1/2, then x@W+b, then log_softmax.
// N=100000, D=64, C=40, E=1600000.
//
// R11: R10 structure with the build phase re-parallelized.
//  - scale_x un-fused (R10's fusion strangled it: 25.6MB of x reads through
//    196 low-occupancy blocks -> 72us build_csr). Full-grid streaming kernel.
//  - build_csr buckets halved to 256 rows: 391 blocks, ~26KB LDS ->= 6
//    blocks/CU by LDS, half-length count/scatter loops. Scatter-run length
//    in binning still ~16 edges = full 64B lines.
//  - Binning: 3-phase, no global atomics (count -> per-bucket scan of
//    per-block counts -> scatter with LDS cursors). Deterministic.
//  - Determinism: per-row cols sorted (insertion sort in LDS) -> accumulate
//    order is a pure function of the edge multiset -> bit-identical replays.
//  - SpMM (best measured structure, R8): quarter-wave per row (16 lanes x
//    uint2 = one 128B bf16 row), 4 predicated groups of 4 -> 16 gathers in
//    flight/wave. Hop 2 fused with 64x40 GEMV + log_softmax.
//  - SpMM is ~11.6 cyc/64B-line (L2/L3 random-fetch ceiling): R8 deeper MLP
//    and R9 chunking both null -> not attacked this round.

#define D_FEAT 64
#define NCLS 40
#define BROWS 256       // rows per bucket
#define BROWS_LOG 8
#define BINCAP 4608     // per-bucket edge capacity (mean 4096, sd ~64 -> 8 sigma)
#define CSRCAP 5376     // per-bucket csr capacity (BINCAP + 3*BROWS)
#define EPT 25          // edges per thread in binning kernels
#define NBLK 256        // padded per-bucket block-count stride (>= 250)

__device__ __forceinline__ unsigned pack_bf16_2(float lo, float hi) {
    unsigned ulo = __float_as_uint(lo);
    unsigned uhi = __float_as_uint(hi);
    ulo = (ulo + 0x7fffu + ((ulo >> 16) & 1u)) >> 16;           // RNE
    uhi = (uhi + 0x7fffu + ((uhi >> 16) & 1u)) & 0xffff0000u;   // RNE
    return uhi | ulo;
}

__device__ __forceinline__ void acc2(unsigned u, float& a, float& b) {
    a += __uint_as_float(u << 16);
    b += __uint_as_float(u & 0xffff0000u);
}

// Phase A: per-(block,bucket) edge counts. blockcounts[bkt*NBLK + blk].
__global__ __launch_bounds__(256) void count_edges_kernel(const int* __restrict__ rows,
                                                          int* __restrict__ blockcounts,
                                                          int e, int nb) {
    __shared__ int cnt[512];
    for (int i = threadIdx.x; i < nb; i += 256) cnt[i] = 0;
    __syncthreads();
    int base = blockIdx.x * (256 * EPT) + threadIdx.x;
#pragma unroll
    for (int k = 0; k < EPT; k++) {
        int idx = base + k * 256;
        if (idx < e) atomicAdd(&cnt[rows[idx] >> BROWS_LOG], 1);
    }
    __syncthreads();
    for (int i = threadIdx.x; i < nb; i += 256)
        blockcounts[i * NBLK + blockIdx.x] = cnt[i];
}

// Phase B: per-bucket exclusive scan of the per-block counts; emits totals.
__global__ __launch_bounds__(256) void scan_bases_kernel(int* __restrict__ blockcounts,
                                                         int* __restrict__ bucket_total,
                                                         int nblocks) {
    __shared__ int sm[256];
    int b = blockIdx.x;
    int t = threadIdx.x;
    int v = (t < nblocks) ? blockcounts[b * NBLK + t] : 0;
    sm[t] = v;
    __syncthreads();
    for (int off = 1; off < 256; off <<= 1) {
        int x = (t >= off) ? sm[t - off] : 0;
        __syncthreads();
        sm[t] += x;
        __syncthreads();
    }
    if (t < nblocks) blockcounts[b * NBLK + t] = sm[t] - v;  // exclusive base
    if (t == 255) bucket_total[b] = sm[255];
}

// Phase C: scatter edges into per-bucket bins using scanned bases (no global
// atomics). Packed entry: (row&255)<<17 | col. (n <= 131072 so col fits 17b.)
__global__ __launch_bounds__(256) void scatter_edges_kernel(const int* __restrict__ rows,
                                                            const int* __restrict__ cols,
                                                            const int* __restrict__ blockcounts,
                                                            unsigned* __restrict__ bins,
                                                            int e, int nb) {
    __shared__ int cur[512];
    for (int i = threadIdx.x; i < nb; i += 256)
        cur[i] = blockcounts[i * NBLK + blockIdx.x];
    __syncthreads();
    int base = blockIdx.x * (256 * EPT) + threadIdx.x;
#pragma unroll
    for (int k = 0; k < EPT; k++) {
        int idx = base + k * 256;
        if (idx < e) {
            int r = rows[idx];
            int b = r >> BROWS_LOG;
            int pos = atomicAdd(&cur[b], 1);  // LDS atomic only
            bins[(size_t)b * BINCAP + pos] =
                ((unsigned)(r & (BROWS - 1)) << 17) | (unsigned)cols[idx];
        }
    }
}

// One 256-thread block per 256-row bucket: LDS count -> dis; scan (pad-4);
// LDS scatter; per-row insertion sort (determinism); int4 copy-out.
__global__ __launch_bounds__(256) void build_csr_kernel(const unsigned* __restrict__ bins,
                                                        const int* __restrict__ bucket_total,
                                                        int* __restrict__ csr_col,
                                                        uint2* __restrict__ row_info,
                                                        float* __restrict__ dis, int n) {
    __shared__ int cnt[BROWS];
    __shared__ int sm[BROWS];
    __shared__ int cur[BROWS];
    __shared__ int lcsr[CSRCAP];  // 21 KB; total ~24 KB
    int b = blockIdx.x;
    int tid = threadIdx.x;
    int m = bucket_total[b];
    cnt[tid] = 0;
    __syncthreads();
    const unsigned* bp = bins + (size_t)b * BINCAP;
    for (int i = tid; i < m; i += 256) atomicAdd(&cnt[bp[i] >> 17], 1);
    __syncthreads();
    int c = cnt[tid];
    int padded = (c + 3) & ~3;
    int r = b * BROWS + tid;
    if (r < n) dis[r] = rsqrtf(1.0f + (float)c);
    sm[tid] = padded;
    __syncthreads();
    for (int off = 1; off < 256; off <<= 1) {
        int t = (tid >= off) ? sm[tid - off] : 0;
        __syncthreads();
        sm[tid] += t;
        __syncthreads();
    }
    int off0 = sm[tid] - padded;  // exclusive scan
    cur[tid] = off0;
    if (r < n) row_info[r] = make_uint2((unsigned)(b * CSRCAP + off0), (unsigned)padded);
    __syncthreads();
    for (int i = tid; i < m; i += 256) {
        unsigned u = bp[i];
        int pos = atomicAdd(&cur[u >> 17], 1);
        lcsr[pos] = (int)(u & 0x1FFFFu);
    }
    __syncthreads();
    // Per-row insertion sort (deterministic multiset order) + dummy pad.
    for (int i2 = off0 + 1; i2 < off0 + c; i2++) {
        int key = lcsr[i2];
        int j = i2 - 1;
        while (j >= off0 && lcsr[j] > key) { lcsr[j + 1] = lcsr[j]; j--; }
        lcsr[j + 1] = key;
    }
    for (int j = off0 + c; j < off0 + padded; j++) lcsr[j] = n;
    __syncthreads();
    int tot = sm[BROWS - 1];  // total padded slots (multiple of 4)
    int4* cp4 = (int4*)(csr_col + (size_t)b * CSRCAP);
    const int4* l4 = (const int4*)lcsr;
    for (int i = tid; i < (tot >> 2); i += 256) cp4[i] = l4[i];
}

// xs0[i] = bf16(dis[i] * x[i,:]) packed 2/dword; dummy rows (n) of BOTH xs
// arrays zeroed (pad slots gather row n).
__global__ void scale_x_kernel(const float* __restrict__ x, const float* __restrict__ dis,
                               unsigned* __restrict__ xs0, unsigned* __restrict__ xs1, int n) {
    int i = blockIdx.x * blockDim.x + threadIdx.x;  // over (n+1)*32 dwords
    int total = (n + 1) * (D_FEAT / 2);
    if (i >= total) return;
    int node = i >> 5;
    if (node < n) {
        float s = dis[node];
        float2 v = ((const float2*)x)[i];
        xs0[i] = pack_bf16_2(s * v.x, s * v.y);
    } else {
        xs0[i] = 0u;
        xs1[i] = 0u;  // dummy row of hop-1 output
    }
}

// Gather 16 slots (4 predicated groups of 4) for one quarter's row chunk.
#define GATHER16(cp, xs_in, ql, base, len)                                  \
    uint2 u0 = make_uint2(0u, 0u), u1 = u0, u2 = u0, u3 = u0;               \
    uint2 u4 = u0, u5 = u0, u6 = u0, u7 = u0;                               \
    uint2 u8 = u0, u9 = u0, u10 = u0, u11 = u0;                             \
    uint2 u12 = u0, u13 = u0, u14 = u0, u15 = u0;                           \
    if (base < len) {                                                       \
        uint4 cv = cp[(base >> 2) + 0];                                     \
        u0 = xs_in[cv.x * 16 + ql]; u1 = xs_in[cv.y * 16 + ql];             \
        u2 = xs_in[cv.z * 16 + ql]; u3 = xs_in[cv.w * 16 + ql];             \
    }                                                                       \
    if (base + 4 < len) {                                                   \
        uint4 cv = cp[(base >> 2) + 1];                                     \
        u4 = xs_in[cv.x * 16 + ql]; u5 = xs_in[cv.y * 16 + ql];             \
        u6 = xs_in[cv.z * 16 + ql]; u7 = xs_in[cv.w * 16 + ql];             \
    }                                                                       \
    if (base + 8 < len) {                                                   \
        uint4 cv = cp[(base >> 2) + 2];                                     \
        u8 = xs_in[cv.x * 16 + ql]; u9 = xs_in[cv.y * 16 + ql];             \
        u10 = xs_in[cv.z * 16 + ql]; u11 = xs_in[cv.w * 16 + ql];           \
    }                                                                       \
    if (base + 12 < len) {                                                  \
        uint4 cv = cp[(base >> 2) + 3];                                     \
        u12 = xs_in[cv.x * 16 + ql]; u13 = xs_in[cv.y * 16 + ql];           \
        u14 = xs_in[cv.z * 16 + ql]; u15 = xs_in[cv.w * 16 + ql];           \
    }                                                                       \
    acc2(u0.x, h0, h1); acc2(u0.y, h2, h3);                                 \
    acc2(u1.x, h0, h1); acc2(u1.y, h2, h3);                                 \
    acc2(u2.x, h0, h1); acc2(u2.y, h2, h3);                                 \
    acc2(u3.x, h0, h1); acc2(u3.y, h2, h3);                                 \
    acc2(u4.x, h0, h1); acc2(u4.y, h2, h3);                                 \
    acc2(u5.x, h0, h1); acc2(u5.y, h2, h3);                                 \
    acc2(u6.x, h0, h1); acc2(u6.y, h2, h3);                                 \
    acc2(u7.x, h0, h1); acc2(u7.y, h2, h3);                                 \
    acc2(u8.x, h0, h1); acc2(u8.y, h2, h3);                                 \
    acc2(u9.x, h0, h1); acc2(u9.y, h2, h3);                                 \
    acc2(u10.x, h0, h1); acc2(u10.y, h2, h3);                               \
    acc2(u11.x, h0, h1); acc2(u11.y, h2, h3);                               \
    acc2(u12.x, h0, h1); acc2(u12.y, h2, h3);                               \
    acc2(u13.x, h0, h1); acc2(u13.y, h2, h3);                               \
    acc2(u14.x, h0, h1); acc2(u14.y, h2, h3);                               \
    acc2(u15.x, h0, h1); acc2(u15.y, h2, h3);

// Hop 1: xs1[r,:] = bf16( dis[r]^2 * ( xs0[r,:] + sum_c xs0[c,:] ) ).
// Quarter q owns row 4*wave+q; lane (q,ql) holds features 4ql..4ql+3.
__global__ __launch_bounds__(256) void spmm_hop1_kernel(const uint2* __restrict__ xs_in,
                                                        uint2* __restrict__ xs_out,
                                                        const uint2* __restrict__ row_info,
                                                        const int* __restrict__ csr_col,
                                                        const float* __restrict__ dis, int n) {
    int wave = (blockIdx.x * blockDim.x + threadIdx.x) >> 6;
    int lane = threadIdx.x & 63;
    int q = lane >> 4, ql = lane & 15;
    int r = wave * 4 + q;
    bool valid = r < n;
    int s = 0, len = 0;
    if (valid) { uint2 info = row_info[r]; s = (int)info.x; len = (int)info.y; }
    int maxlen = len;
    maxlen = max(maxlen, __shfl_xor(maxlen, 16, 64));
    maxlen = max(maxlen, __shfl_xor(maxlen, 32, 64));

    float h0 = 0.f, h1 = 0.f, h2 = 0.f, h3 = 0.f;
    const uint4* cp = (const uint4*)(csr_col + s);  // s is a multiple of 4
    for (int base = 0; base < maxlen; base += 16) {
        GATHER16(cp, xs_in, ql, base, len)
    }
    if (valid) {
        uint2 us = xs_in[r * 16 + ql];  // self term
        acc2(us.x, h0, h1); acc2(us.y, h2, h3);
        float dr = dis[r];
        float dr2 = dr * dr;
        xs_out[r * 16 + ql] = make_uint2(pack_bf16_2(dr2 * h0, dr2 * h1),
                                         pack_bf16_2(dr2 * h2, dr2 * h3));
    }
}

// Hop 2 fused with logits + log_softmax. h2[r,:] = dis[r]*(xs1[r,:]+sum_c xs1[c,:]).
// GEMV: lane ql covers classes ql, ql+16, (ql<8) ql+32; features broadcast via
// per-lane-source __shfl within the quarter.
__global__ __launch_bounds__(256) void spmm_logits_kernel(const uint2* __restrict__ xs_in,
                                                          const uint2* __restrict__ row_info,
                                                          const int* __restrict__ csr_col,
                                                          const float* __restrict__ dis,
                                                          const float* __restrict__ W,
                                                          const float* __restrict__ b,
                                                          float* __restrict__ out, int n) {
    __shared__ float Wl[D_FEAT * NCLS];
    __shared__ float bl[NCLS];
    for (int i = threadIdx.x; i < D_FEAT * NCLS; i += blockDim.x) Wl[i] = W[i];
    for (int i = threadIdx.x; i < NCLS; i += blockDim.x) bl[i] = b[i];
    __syncthreads();

    int wave = (blockIdx.x * blockDim.x + threadIdx.x) >> 6;
    int lane = threadIdx.x & 63;
    int q = lane >> 4, ql = lane & 15;
    int r = wave * 4 + q;
    bool valid = r < n;
    int s = 0, len = 0;
    if (valid) { uint2 info = row_info[r]; s = (int)info.x; len = (int)info.y; }
    int maxlen = len;
    maxlen = max(maxlen, __shfl_xor(maxlen, 16, 64));
    maxlen = max(maxlen, __shfl_xor(maxlen, 32, 64));

    float h0 = 0.f, h1 = 0.f, h2 = 0.f, h3 = 0.f;
    const uint4* cp = (const uint4*)(csr_col + s);
    for (int base = 0; base < maxlen; base += 16) {
        GATHER16(cp, xs_in, ql, base, len)
    }

    float y0, y1, y2;
    {
        uint2 us = valid ? xs_in[r * 16 + ql] : make_uint2(0u, 0u);  // self term
        acc2(us.x, h0, h1); acc2(us.y, h2, h3);
        float dr = valid ? dis[r] : 0.f;
        h0 *= dr; h1 *= dr; h2 *= dr; h3 *= dr;

        int c0 = ql, c1 = ql + 16;
        int c2 = (ql < 8) ? (ql + 32) : ql;  // dup addr -> broadcast, no conflict
        y0 = bl[c0]; y1 = bl[c1]; y2 = bl[c2];
        int qbase = q << 4;
#pragma unroll
        for (int d = 0; d < D_FEAT; d++) {
            int src = qbase + (d >> 2);
            float xv;
            switch (d & 3) {
                case 0: xv = __shfl(h0, src, 64); break;
                case 1: xv = __shfl(h1, src, 64); break;
                case 2: xv = __shfl(h2, src, 64); break;
                default: xv = __shfl(h3, src, 64); break;
            }
            y0 += xv * Wl[d * NCLS + c0];
            y1 += xv * Wl[d * NCLS + c1];
            y2 += xv * Wl[d * NCLS + c2];
        }
    }

    bool has3 = (ql < 8);
    float m = fmaxf(y0, y1);
    if (has3) m = fmaxf(m, y2);
#pragma unroll
    for (int o = 8; o > 0; o >>= 1) m = fmaxf(m, __shfl_xor(m, o, 64));
    float sm = __expf(y0 - m) + __expf(y1 - m) + (has3 ? __expf(y2 - m) : 0.f);
#pragma unroll
    for (int o = 8; o > 0; o >>= 1) sm += __shfl_xor(sm, o, 64);
    float lse = m + __logf(sm);

    if (valid) {
        float* op = out + (long long)r * NCLS;
        op[ql] = y0 - lse;
        op[ql + 16] = y1 - lse;
        if (has3) op[ql + 32] = y2 - lse;
    }
}

extern "C" void kernel_launch(void* const* d_in, const int* in_sizes, int n_in,
                              void* d_out, int out_size, void* d_ws, size_t ws_size,
                              hipStream_t stream) {
    const float* x  = (const float*)d_in[0];
    const int*   ei = (const int*)d_in[1];   // [2, E] flat: rows then cols (int32)
    const float* W  = (const float*)d_in[2]; // [64, 40]
    const float* b  = (const float*)d_in[3]; // [40]
    float* out = (float*)d_out;

    const int n = in_sizes[0] / D_FEAT;      // 100000
    const int e = in_sizes[1] / 2;           // 1600000
    const int nb = (n + BROWS - 1) / BROWS;  // 391
    const int eblocks = (e + 256 * EPT - 1) / (256 * EPT);  // 250

    const int* rows = ei;
    const int* cols = ei + e;

    // ws layout (int units, segments 256-int aligned):
    //   bucket_total[512] | blockcounts[nb*NBLK] | dis[n] | row_info[n] |
    //   bins[nb*BINCAP] | csr_col[nb*CSRCAP] | xs0 | xs1     (~46 MB)
    size_t na = ((size_t)n + 256) & ~(size_t)255;
    int*      bucket_total = (int*)d_ws;
    int*      blockcounts  = bucket_total + 512;
    float*    dis          = (float*)(blockcounts + (size_t)nb * NBLK + 256);
    uint2*    row_info     = (uint2*)(dis + na);
    unsigned* bins         = (unsigned*)(row_info + na);
    int*      csr_col      = (int*)(bins + (size_t)nb * BINCAP);
    unsigned* xs0          = (unsigned*)(csr_col + (size_t)nb * CSRCAP + 256);
    unsigned* xs1          = xs0 + (size_t)(n + 1) * (D_FEAT / 2);

    const int BS = 256;

    count_edges_kernel<<<eblocks, BS, 0, stream>>>(rows, blockcounts, e, nb);
    scan_bases_kernel<<<nb, BS, 0, stream>>>(blockcounts, bucket_total, eblocks);
    scatter_edges_kernel<<<eblocks, BS, 0, stream>>>(rows, cols, blockcounts, bins, e, nb);
    build_csr_kernel<<<nb, BS, 0, stream>>>(bins, bucket_total, csr_col, row_info, dis, n);
    {
        int tot = (n + 1) * (D_FEAT / 2);
        scale_x_kernel<<<(tot + BS - 1) / BS, BS, 0, stream>>>(x, dis, xs0, xs1, n);
    }

    int nwaves = (n + 3) / 4;                 // 25000 waves, 4 rows each
    int blocks = (nwaves * 64 + BS - 1) / BS; // 6250
    spmm_hop1_kernel<<<blocks, BS, 0, stream>>>((const uint2*)xs0, (uint2*)xs1,
                                                row_info, csr_col, dis, n);
    spmm_logits_kernel<<<blocks, BS, 0, stream>>>((const uint2*)xs1, row_info, csr_col,
                                                  dis, W, b, out, n);
}